// Round 13
// baseline (865.669 us; speedup 1.0000x reference)
//
#include <hip/hip_runtime.h>
#include <float.h>

#define BLK 256
#define NB 8
#define NPTS 8192
#define CSPLIT 2
#define TILES_PER_CHUNK (NPTS / 32 / CSPLIT)   // 128 col-tiles per chunk

typedef short bf16x8 __attribute__((ext_vector_type(8)));   // 8 bf16 = 4 VGPRs (guide §3 verified type)
typedef float f32x16 __attribute__((ext_vector_type(16)));  // 32x32 accumulator

static __device__ __forceinline__ unsigned short f2bf(float f) {   // RNE f32->bf16
    union { float f; unsigned int u; } v; v.f = f;
    unsigned int u = v.u + 0x7FFFu + ((v.u >> 16) & 1u);
    return (unsigned short)(u >> 16);
}
static __device__ __forceinline__ float bf2f(unsigned short h) {
    union { unsigned int u; float f; } v; v.u = ((unsigned int)h) << 16;
    return v.f;
}

// out <- +INF bits so atomicMin-as-int accumulates float mins (values >= ~-1e-3;
// tiny negatives lose/win within threshold — argued r10, passed r10/r11).
__global__ __launch_bounds__(BLK) void init_out(int* __restrict__ outI, int n) {
    const int i = blockIdx.x * BLK + threadIdx.x;
    if (i < n) outI[i] = 0x7F800000;
}

// Preprocess both point sets into K=16 bf16 slot layout [point][16]:
//   A (xyz1, query role):  [qh0..2, ql0..2, qh0..2, ql0..2, 1, 1, x2h, x2l]
//   B (xyz2, target role): [th0..2, th0..2, tl0..2, tl0..2, wh, wl, 1, 1]
// with t = -2*y, w = ||y||^2, (h,l) = bf16 hi/lo split.
// Sum_k A_k*B_k = -2 x.y + ||y||^2 + ||x||^2 = squared distance (err ~2^-18).
__global__ __launch_bounds__(BLK) void prep_kernel(
    const float* __restrict__ xyz1, const float* __restrict__ xyz2,
    unsigned short* __restrict__ Aq, unsigned short* __restrict__ Bt, int npts)
{
    const int i = blockIdx.x * BLK + threadIdx.x;
    if (i >= npts) return;
    const unsigned short one = 0x3F80;
    {
        const float x0 = xyz1[3*(size_t)i], x1 = xyz1[3*(size_t)i+1], x2 = xyz1[3*(size_t)i+2];
        const unsigned short h0 = f2bf(x0), h1 = f2bf(x1), h2 = f2bf(x2);
        const unsigned short l0 = f2bf(x0 - bf2f(h0)), l1 = f2bf(x1 - bf2f(h1)), l2 = f2bf(x2 - bf2f(h2));
        const float q2 = fmaf(x0, x0, fmaf(x1, x1, x2 * x2));
        const unsigned short q2h = f2bf(q2), q2l = f2bf(q2 - bf2f(q2h));
        unsigned short* o = Aq + 16*(size_t)i;
        o[0]=h0; o[1]=h1; o[2]=h2; o[3]=l0; o[4]=l1; o[5]=l2;
        o[6]=h0; o[7]=h1; o[8]=h2; o[9]=l0; o[10]=l1; o[11]=l2;
        o[12]=one; o[13]=one; o[14]=q2h; o[15]=q2l;
    }
    {
        const float y0 = xyz2[3*(size_t)i], y1 = xyz2[3*(size_t)i+1], y2 = xyz2[3*(size_t)i+2];
        const float t0 = -2.f*y0, t1 = -2.f*y1, t2 = -2.f*y2;
        const unsigned short h0 = f2bf(t0), h1 = f2bf(t1), h2 = f2bf(t2);
        const unsigned short l0 = f2bf(t0 - bf2f(h0)), l1 = f2bf(t1 - bf2f(h1)), l2 = f2bf(t2 - bf2f(h2));
        const float w = fmaf(y0, y0, fmaf(y1, y1, y2 * y2));
        const unsigned short wh = f2bf(w), wl = f2bf(w - bf2f(wh));
        unsigned short* o = Bt + 16*(size_t)i;
        o[0]=h0; o[1]=h1; o[2]=h2; o[3]=h0; o[4]=h1; o[5]=h2;
        o[6]=l0; o[7]=l1; o[8]=l2; o[9]=l0; o[10]=l1; o[11]=l2;
        o[12]=wh; o[13]=wl; o[14]=one; o[15]=one;
    }
}

// Main: each wave owns a 32-row strip of xyz1 and streams 32-col target tiles.
// D tile (32x32 squared distances) from ONE MFMA; row-mins (dist1) fold
// in-register across tiles; col-mins (dist2) fold per tile + atomicMin.
// No LDS. A/B frag reads use identical [point][2-half] layout (permutation-safe).
__global__ __launch_bounds__(BLK) void chamfer_mfma(
    const bf16x8* __restrict__ Aq, const bf16x8* __restrict__ Bt,
    int* __restrict__ outI)
{
    const int wave  = threadIdx.x >> 6;
    const int lane  = threadIdx.x & 63;
    const int l31   = lane & 31;
    const int khalf = lane >> 5;

    const int batch = blockIdx.y;
    const int chunk = blockIdx.z;
    const int rowbase = (blockIdx.x * 4 + wave) * 32;

    // A fragment: row = rowbase + l31, k-half = khalf (held for whole kernel)
    const bf16x8 afrag = Aq[((size_t)batch * NPTS + rowbase + l31) * 2 + khalf];

    float rowacc[16];
#pragma unroll
    for (int i = 0; i < 16; ++i) rowacc[i] = FLT_MAX;

    const f32x16 zero = {};            // loop-invariant C operand (no per-tile init)
    const size_t bbase = (size_t)batch * NPTS;
    const int* dist2base = outI + (size_t)NB * NPTS;   // second output block

    int mcur = chunk * TILES_PER_CHUNK * 32 + l31;
    bf16x8 b1 = Bt[(bbase + mcur     ) * 2 + khalf];
    bf16x8 b2 = Bt[(bbase + mcur + 32) * 2 + khalf];

    for (int t = 0; t < TILES_PER_CHUNK; t += 2) {
        const int mnext = (t + 2 < TILES_PER_CHUNK) ? mcur + 64 : mcur;  // uniform clamp
        bf16x8 nb1 = Bt[(bbase + mnext     ) * 2 + khalf];
        bf16x8 nb2 = Bt[(bbase + mnext + 32) * 2 + khalf];

        f32x16 d1 = __builtin_amdgcn_mfma_f32_32x32x16_bf16(afrag, b1, zero, 0, 0, 0);
        f32x16 d2 = __builtin_amdgcn_mfma_f32_32x32x16_bf16(afrag, b2, zero, 0, 0, 0);

        // dist1 fold: rowacc[i] = min3(d1[i], d2[i], rowacc[i])  (r5/r11-proven asm)
#pragma unroll
        for (int i = 0; i < 16; ++i) {
            const float a = d1[i], b = d2[i];
            asm("v_min3_f32 %0, %1, %2, %3"
                : "=v"(rowacc[i]) : "v"(a), "v"(b), "0"(rowacc[i]));
        }
        // dist2 fold per tile: min over this lane's 16 rows of col mcur(+32);
        // lanes l and l+32 (same col, other row-half) both atomic — HW merges.
        {
            float m0 = fminf((float)d1[0], (float)d1[1]);
#pragma unroll
            for (int i = 2; i < 16; i += 2) {
                const float a = d1[i], b = d1[i+1];
                asm("v_min3_f32 %0, %1, %2, %3" : "=v"(m0) : "v"(a), "v"(b), "0"(m0));
            }
            atomicMin((int*)dist2base + bbase + mcur, __float_as_int(m0));
        }
        {
            float m0 = fminf((float)d2[0], (float)d2[1]);
#pragma unroll
            for (int i = 2; i < 16; i += 2) {
                const float a = d2[i], b = d2[i+1];
                asm("v_min3_f32 %0, %1, %2, %3" : "=v"(m0) : "v"(a), "v"(b), "0"(m0));
            }
            atomicMin((int*)dist2base + bbase + mcur + 32, __float_as_int(m0));
        }
        b1 = nb1; b2 = nb2; mcur += 64;
    }

    // dist1 sink: verified C/D layout row = (reg&3) + 8*(reg>>2) + 4*khalf.
    // All 32 lanes of each half hold partials over disjoint col subsets -> atomic merge.
#pragma unroll
    for (int i = 0; i < 16; ++i) {
        const int row = (i & 3) + 8 * (i >> 2) + 4 * khalf;
        atomicMin(outI + (size_t)batch * NPTS + rowbase + row, __float_as_int(rowacc[i]));
    }
}

// Safety fallback if ws is too small (r1-style direct kernel).
__global__ __launch_bounds__(BLK) void chamfer_fallback(
    const float* __restrict__ xyz1, const float* __restrict__ xyz2,
    float* __restrict__ out, int B, int N, int M)
{
    const int dir = blockIdx.z;
    const int b   = blockIdx.y;
    const float* Q = (dir == 0) ? xyz1 : xyz2;
    const float* T = (dir == 0) ? xyz2 : xyz1;
    const int nQ = (dir == 0) ? N : M;
    const int nT = (dir == 0) ? M : N;
    const int i = blockIdx.x * BLK + threadIdx.x;

    float x0 = 0.f, x1 = 0.f, x2 = 0.f;
    if (i < nQ) {
        const float* q = Q + ((size_t)b * nQ + i) * 3;
        x0 = q[0]; x1 = q[1]; x2 = q[2];
    }
    float best = FLT_MAX;
    for (int jj = 0; jj < nT; ++jj) {
        const float* t = T + ((size_t)b * nT + jj) * 3;
        float t0 = t[0] - x0, t1 = t[1] - x1, t2 = t[2] - x2;
        best = fminf(best, fmaf(t0, t0, fmaf(t1, t1, t2 * t2)));
    }
    if (i < nQ) {
        const size_t off = (dir == 0) ? ((size_t)b * N + i)
                                      : ((size_t)B * N + (size_t)b * M + i);
        out[off] = best;
    }
}

extern "C" void kernel_launch(void* const* d_in, const int* in_sizes, int n_in,
                              void* d_out, int out_size, void* d_ws, size_t ws_size,
                              hipStream_t stream) {
    const float* xyz1 = (const float*)d_in[0];
    const float* xyz2 = (const float*)d_in[1];

    const int npts = NB * NPTS;                       // 65536 points per set
    const size_t a_bytes = (size_t)npts * 32;         // 16 bf16 slots per point (2 MB)
    const size_t b_bytes = (size_t)npts * 32;

    if (ws_size >= a_bytes + b_bytes) {
        unsigned short* Aq = (unsigned short*)d_ws;
        unsigned short* Bt = (unsigned short*)((char*)d_ws + a_bytes);
        int* outI = (int*)d_out;
        const int outn = 2 * NB * NPTS;

        init_out<<<(outn + BLK - 1) / BLK, BLK, 0, stream>>>(outI, outn);
        prep_kernel<<<(npts + BLK - 1) / BLK, BLK, 0, stream>>>(xyz1, xyz2, Aq, Bt, npts);

        dim3 grid(NPTS / 32 / 4, NB, CSPLIT);         // (64, 8, 2): 4 waves/block = 4 row-strips
        chamfer_mfma<<<grid, dim3(BLK, 1, 1), 0, stream>>>(
            (const bf16x8*)Aq, (const bf16x8*)Bt, outI);
    } else {
        dim3 grid((NPTS + BLK - 1) / BLK, NB, 2);
        chamfer_fallback<<<grid, dim3(BLK, 1, 1), 0, stream>>>(
            xyz1, xyz2, (float*)d_out, NB, NPTS, NPTS);
    }
}

// Round 17
// 74.143 us; speedup vs baseline: 11.6756x; 11.6756x over previous
//
#include <hip/hip_runtime.h>
#include <float.h>

#define BLK 256
#define NB 8
#define NPTS 8192
#define WPB 4      // waves per block
#define RPW 2      // 32-row strips per wave
#define CSPLIT 2   // column chunks per (batch, dir)
#define TPC (NPTS / 32 / CSPLIT)   // 128 col-tiles per chunk

typedef short bf16x8 __attribute__((ext_vector_type(8)));
typedef float f32x16 __attribute__((ext_vector_type(16)));

static __device__ __forceinline__ unsigned short f2bf(float f) {   // RNE f32->bf16
    union { float f; unsigned int u; } v; v.f = f;
    unsigned int u = v.u + 0x7FFFu + ((v.u >> 16) & 1u);
    return (unsigned short)(u >> 16);
}
static __device__ __forceinline__ float bf2f(unsigned short h) {
    union { unsigned int u; float f; } v; v.u = ((unsigned int)h) << 16;
    return v.f;
}

__global__ __launch_bounds__(BLK) void init_out(int* __restrict__ outI, int n) {
    const int i = blockIdx.x * BLK + threadIdx.x;
    if (i < n) outI[i] = 0x7F800000;   // +inf bits; atomicMin-as-int = float min (r10-r13 proven)
}

// Emit BOTH layouts for BOTH point sets (K=16 bf16 slots per point; r13-verified):
//   query layout:  [qh0..2, ql0..2, qh0..2, ql0..2, 1, 1, x2h, x2l]
//   target layout: [th0..2, th0..2, tl0..2, tl0..2, wh, wl, 1, 1], t = -2y, w=||y||^2
// Sum_k A_k*B_k = ||x||^2 + ||y||^2 - 2 x.y  (bf16 products exact in f32).
__global__ __launch_bounds__(BLK) void prep_kernel(
    const float* __restrict__ xyz1, const float* __restrict__ xyz2,
    unsigned short* __restrict__ Aq1, unsigned short* __restrict__ Bt1,
    unsigned short* __restrict__ Aq2, unsigned short* __restrict__ Bt2, int npts)
{
    const int i = blockIdx.x * BLK + threadIdx.x;
    if (i >= npts) return;
    const unsigned short one = 0x3F80;
    const float* srcs[2] = { xyz1, xyz2 };
    unsigned short* aouts[2] = { Aq1, Aq2 };
    unsigned short* bouts[2] = { Bt1, Bt2 };
#pragma unroll
    for (int s = 0; s < 2; ++s) {
        const float p0 = srcs[s][3*(size_t)i], p1 = srcs[s][3*(size_t)i+1], p2 = srcs[s][3*(size_t)i+2];
        // query layout
        {
            const unsigned short h0 = f2bf(p0), h1 = f2bf(p1), h2 = f2bf(p2);
            const unsigned short l0 = f2bf(p0 - bf2f(h0)), l1 = f2bf(p1 - bf2f(h1)), l2 = f2bf(p2 - bf2f(h2));
            const float q2 = fmaf(p0, p0, fmaf(p1, p1, p2 * p2));
            const unsigned short q2h = f2bf(q2), q2l = f2bf(q2 - bf2f(q2h));
            unsigned short* o = aouts[s] + 16*(size_t)i;
            o[0]=h0; o[1]=h1; o[2]=h2; o[3]=l0; o[4]=l1; o[5]=l2;
            o[6]=h0; o[7]=h1; o[8]=h2; o[9]=l0; o[10]=l1; o[11]=l2;
            o[12]=one; o[13]=one; o[14]=q2h; o[15]=q2l;
        }
        // target layout
        {
            const float t0 = -2.f*p0, t1 = -2.f*p1, t2 = -2.f*p2;
            const unsigned short h0 = f2bf(t0), h1 = f2bf(t1), h2 = f2bf(t2);
            const unsigned short l0 = f2bf(t0 - bf2f(h0)), l1 = f2bf(t1 - bf2f(h1)), l2 = f2bf(t2 - bf2f(h2));
            const float w = fmaf(p0, p0, fmaf(p1, p1, p2 * p2));
            const unsigned short wh = f2bf(w), wl = f2bf(w - bf2f(wh));
            unsigned short* o = bouts[s] + 16*(size_t)i;
            o[0]=h0; o[1]=h1; o[2]=h2; o[3]=h0; o[4]=h1; o[5]=h2;
            o[6]=l0; o[7]=l1; o[8]=l2; o[9]=l0; o[10]=l1; o[11]=l2;
            o[12]=wh; o[13]=wl; o[14]=one; o[15]=one;
        }
    }
}

// Both chamfer directions as ROW-min MFMA passes (dir selects operand roles).
// Row-mins fold in registers across all tiles (2 col-tiles per iteration via
// min3: acc[i] = min3(dA[i], dB[i], acc[i]) — rows stay distinct). Epilogue:
// 5-step shfl_xor butterfly within 32-lane col-groups + ONE atomic per
// (row, chunk). 262K atomics total vs r13's 33.5M.
__global__ __launch_bounds__(BLK) void chamfer_mfma(
    const bf16x8* __restrict__ Aq1, const bf16x8* __restrict__ Bt1,
    const bf16x8* __restrict__ Aq2, const bf16x8* __restrict__ Bt2,
    int* __restrict__ outI)
{
    const int wave  = threadIdx.x >> 6;
    const int lane  = threadIdx.x & 63;
    const int l31   = lane & 31;
    const int khalf = lane >> 5;

    const int z     = blockIdx.z;          // [0, 2*CSPLIT)
    const int dir   = z >> 1;
    const int chunk = z & (CSPLIT - 1);
    const int batch = blockIdx.y;

    const bf16x8* __restrict__ A  = dir ? Aq2 : Aq1;
    const bf16x8* __restrict__ Bt = dir ? Bt1 : Bt2;
    int* outbase = outI + (size_t)dir * NB * NPTS + (size_t)batch * NPTS;

    const size_t pbase = (size_t)batch * NPTS;
    const int r0 = (blockIdx.x * WPB + wave) * (RPW * 32);

    // Two A fragments (rows r0..r0+31, r0+32..r0+63), held all kernel.
    const bf16x8 afrag0 = A[(pbase + r0      + l31) * 2 + khalf];
    const bf16x8 afrag1 = A[(pbase + r0 + 32 + l31) * 2 + khalf];

    float acc0[16], acc1[16];
#pragma unroll
    for (int i = 0; i < 16; ++i) { acc0[i] = FLT_MAX; acc1[i] = FLT_MAX; }

    const f32x16 zero = {};
    int mcur = chunk * (NPTS / CSPLIT) + l31;   // tile col for this lane
    bf16x8 bA = Bt[(pbase + mcur     ) * 2 + khalf];
    bf16x8 bB = Bt[(pbase + mcur + 32) * 2 + khalf];

    for (int t = 0; t < TPC; t += 2) {          // 2 col-tiles per iteration
        const int mnext = (t + 2 < TPC) ? mcur + 64 : mcur;   // uniform clamp
        const bf16x8 nA = Bt[(pbase + mnext     ) * 2 + khalf];
        const bf16x8 nB = Bt[(pbase + mnext + 32) * 2 + khalf];

        const f32x16 d0A = __builtin_amdgcn_mfma_f32_32x32x16_bf16(afrag0, bA, zero, 0, 0, 0);
        const f32x16 d0B = __builtin_amdgcn_mfma_f32_32x32x16_bf16(afrag0, bB, zero, 0, 0, 0);
        const f32x16 d1A = __builtin_amdgcn_mfma_f32_32x32x16_bf16(afrag1, bA, zero, 0, 0, 0);
        const f32x16 d1B = __builtin_amdgcn_mfma_f32_32x32x16_bf16(afrag1, bB, zero, 0, 0, 0);

#pragma unroll
        for (int i = 0; i < 16; ++i) {          // rows distinct; 2 candidates/op
            const float a = d0A[i], b = d0B[i];
            asm("v_min3_f32 %0, %1, %2, %3" : "=v"(acc0[i]) : "v"(a), "v"(b), "0"(acc0[i]));
        }
#pragma unroll
        for (int i = 0; i < 16; ++i) {
            const float a = d1A[i], b = d1B[i];
            asm("v_min3_f32 %0, %1, %2, %3" : "=v"(acc1[i]) : "v"(a), "v"(b), "0"(acc1[i]));
        }
        bA = nA; bB = nB; mcur = mnext;
    }

    // Epilogue: butterfly min over the 32 lanes (cols) of each khalf group,
    // then lane l31==i issues the single atomic for its row. khalf 0/1 hold
    // DIFFERENT rows (row = (i&3)+8*(i>>2)+4*khalf) — no double-writes.
#pragma unroll
    for (int i = 0; i < 16; ++i) {
        float v0 = acc0[i], v1 = acc1[i];
#pragma unroll
        for (int off = 1; off < 32; off <<= 1) {
            v0 = fminf(v0, __shfl_xor(v0, off, 64));
            v1 = fminf(v1, __shfl_xor(v1, off, 64));
        }
        if (l31 == i) {
            const int row = (i & 3) + 8 * (i >> 2) + 4 * khalf;
            atomicMin(outbase + r0      + row, __float_as_int(v0));
            atomicMin(outbase + r0 + 32 + row, __float_as_int(v1));
        }
    }
}

// Safety fallback if ws is too small.
__global__ __launch_bounds__(BLK) void chamfer_fallback(
    const float* __restrict__ xyz1, const float* __restrict__ xyz2,
    float* __restrict__ out, int B, int N, int M)
{
    const int dir = blockIdx.z;
    const int b   = blockIdx.y;
    const float* Q = (dir == 0) ? xyz1 : xyz2;
    const float* T = (dir == 0) ? xyz2 : xyz1;
    const int nQ = (dir == 0) ? N : M;
    const int nT = (dir == 0) ? M : N;
    const int i = blockIdx.x * BLK + threadIdx.x;

    float x0 = 0.f, x1 = 0.f, x2 = 0.f;
    if (i < nQ) {
        const float* q = Q + ((size_t)b * nQ + i) * 3;
        x0 = q[0]; x1 = q[1]; x2 = q[2];
    }
    float best = FLT_MAX;
    for (int jj = 0; jj < nT; ++jj) {
        const float* t = T + ((size_t)b * nT + jj) * 3;
        float t0 = t[0] - x0, t1 = t[1] - x1, t2 = t[2] - x2;
        best = fminf(best, fmaf(t0, t0, fmaf(t1, t1, t2 * t2)));
    }
    if (i < nQ) {
        const size_t off = (dir == 0) ? ((size_t)b * N + i)
                                      : ((size_t)B * N + (size_t)b * M + i);
        out[off] = best;
    }
}

extern "C" void kernel_launch(void* const* d_in, const int* in_sizes, int n_in,
                              void* d_out, int out_size, void* d_ws, size_t ws_size,
                              hipStream_t stream) {
    const float* xyz1 = (const float*)d_in[0];
    const float* xyz2 = (const float*)d_in[1];

    const int npts = NB * NPTS;                   // 65536 points per set
    const size_t buf = (size_t)npts * 32;         // 2 MB per layout buffer

    if (ws_size >= 4 * buf) {
        unsigned short* Aq1 = (unsigned short*)d_ws;
        unsigned short* Bt1 = (unsigned short*)((char*)d_ws + buf);
        unsigned short* Aq2 = (unsigned short*)((char*)d_ws + 2*buf);
        unsigned short* Bt2 = (unsigned short*)((char*)d_ws + 3*buf);
        int* outI = (int*)d_out;
        const int outn = 2 * NB * NPTS;

        init_out<<<(outn + BLK - 1) / BLK, BLK, 0, stream>>>(outI, outn);
        prep_kernel<<<(npts + BLK - 1) / BLK, BLK, 0, stream>>>(
            xyz1, xyz2, Aq1, Bt1, Aq2, Bt2, npts);

        dim3 grid(NPTS / 32 / (WPB * RPW), NB, 2 * CSPLIT);   // (32, 8, 4)
        chamfer_mfma<<<grid, dim3(BLK, 1, 1), 0, stream>>>(
            (const bf16x8*)Aq1, (const bf16x8*)Bt1,
            (const bf16x8*)Aq2, (const bf16x8*)Bt2, outI);
    } else {
        dim3 grid((NPTS + BLK - 1) / BLK, NB, 2);
        chamfer_fallback<<<grid, dim3(BLK, 1, 1), 0, stream>>>(
            xyz1, xyz2, (float*)d_out, NB, NPTS, NPTS);
    }
}